// Round 1
// baseline (482.426 us; speedup 1.0000x reference)
//
#include <hip/hip_runtime.h>
#include <hip/hip_bf16.h>
#include <stdint.h>

// LSH: project -> sign-bit-pack -> Hamming via xor+popcount -> cos
//
// Layouts:
//   packed codes in d_ws: [12288 rows][16 u64]  (u = rows 0..4095, v = rows 4096..12287)
//   bit b of row n = (dot(emb[n], r[b]) > 0); bit order arbitrary but identical
//   for u and v (ballot: bit i <-> lane i), so xor-popcount Hamming is exact.

#define NBITS   1024
#define DIMK    128
#define NROWS1  4096
#define NROWS2  8192

// ---------------------------------------------------------------------------
// Kernel 1: projection + sign + bit-pack.
// Grid (96, 8): 96 row-blocks x 8 bit-tiles. Block = 256 threads (4 waves).
// Block covers 128 rows x 128 bits x full K=128.
// LDS: r tile [128 bits][128 k] f32 = 64 KB, stored as 32 float4 chunks/row,
// chunk c placed at c ^ (row & 7)  -> conflict-free ds_read_b128 at compute.
// ---------------------------------------------------------------------------
__global__ __launch_bounds__(256, 2) void lsh_project_pack(
    const float4* __restrict__ emb1,
    const float4* __restrict__ emb2,
    const float4* __restrict__ r4,
    unsigned long long* __restrict__ packed)
{
  __shared__ float4 r_lds[128 * 32];

  const int t = threadIdx.x;
  const int w = t >> 6;          // wave 0..3
  const int l = t & 63;          // lane
  const int rowBlk  = blockIdx.x;   // 0..95   (128 rows each)
  const int bitTile = blockIdx.y;   // 0..7    (128 bits each)

  // ---- stage r tile: coalesced global read, swizzled LDS write ----
  {
    int idx = t;
#pragma unroll
    for (int i = 0; i < 16; ++i, idx += 256) {
      const int row = idx >> 5;   // 0..127 (bit within tile)
      const int c   = idx & 31;   // float4 chunk 0..31
      r_lds[row * 32 + (c ^ (row & 7))] = r4[(bitTile * 128 + row) * 32 + c];
    }
  }
  __syncthreads();

  const int half      = w >> 1;                  // row half within block
  const int bit_local = ((w & 1) << 6) + l;      // 0..127
  const int key       = l & 7;                   // swizzle key (== bit_local&7)
  const int rbase     = bit_local * 32;
  const int wordIdx   = bitTile * 2 + (w & 1);   // u64 word within packed row

  const int rowStart = rowBlk * 128;             // global row base of block
  const bool side1   = rowStart < NROWS1;        // uniform: blockIdx-only
  const float4* __restrict__ eb4 = side1 ? emb1 : emb2;
  const int rowBlkOff = side1 ? rowStart : (rowStart - NROWS1);

  for (int g = 0; g < 8; ++g) {
    const int rowLocal0 = half * 64 + g * 8;
    // wave-uniform base index, readfirstlane -> scalar loads (s_load_dwordx4)
    const int ueb = __builtin_amdgcn_readfirstlane((rowBlkOff + rowLocal0) * 32);

    float acc[8];
#pragma unroll
    for (int j = 0; j < 8; ++j) acc[j] = 0.0f;

#pragma unroll 4
    for (int c = 0; c < 32; ++c) {
      const float4 rv = r_lds[rbase + (c ^ key)];
#pragma unroll
      for (int j = 0; j < 8; ++j) {
        const float4 ev = eb4[ueb + j * 32 + c];
        acc[j] = fmaf(ev.x, rv.x, acc[j]);
        acc[j] = fmaf(ev.y, rv.y, acc[j]);
        acc[j] = fmaf(ev.z, rv.z, acc[j]);
        acc[j] = fmaf(ev.w, rv.w, acc[j]);
      }
    }

#pragma unroll
    for (int j = 0; j < 8; ++j) {
      // ballot: bit i of mask = lane i's predicate; lane i owns bit (base+i)
      const unsigned long long m = __ballot(acc[j] > 0.0f);
      if (l == 0) {
        const int grow = rowStart + rowLocal0 + j;   // global packed row
        packed[(size_t)grow * 16 + wordIdx] = m;
      }
    }
  }
}

// ---------------------------------------------------------------------------
// Kernel 2: Hamming (xor + popcount) + cos epilogue.
// Grid (64, 128): 64 n-tiles x 128 m-tiles. Block = 256 threads.
// Block tile: 32 u-rows x 128 v-cols. Thread: 1 u-row (regs) x 16 v-cols.
// v tile staged in LDS (16 KB); per-wave v reads are 2-address broadcasts.
// ---------------------------------------------------------------------------
__global__ __launch_bounds__(256, 4) void lsh_hamming_cos(
    const uint4* __restrict__ up,    // [4096][8]
    const uint4* __restrict__ vp,    // [8192][8]
    const float* __restrict__ pi_in,
    float* __restrict__ out)         // [4096][8192]
{
  __shared__ uint4 v_lds[128 * 8];

  const int t  = threadIdx.x;
  const int n0 = blockIdx.x * 128;
  const int m0 = blockIdx.y * 32;

  // stage v tile: coalesced
#pragma unroll
  for (int i = 0; i < 4; ++i) {
    const int idx = t + i * 256;
    v_lds[idx] = vp[(size_t)n0 * 8 + idx];
  }

  // u row -> registers (L2-resident, one-time per block)
  const int m = m0 + (t & 31);
  uint4 U[8];
#pragma unroll
  for (int c = 0; c < 8; ++c) U[c] = up[(size_t)m * 8 + c];

  __syncthreads();

  const float scale = pi_in[0] * (1.0f / (float)NBITS);
  const int g = t >> 5;                         // n-group 0..7
  float* __restrict__ orow = out + (size_t)m * NROWS2 + n0 + g * 16;

#pragma unroll
  for (int jj = 0; jj < 4; ++jj) {
    float res[4];
#pragma unroll
    for (int j2 = 0; j2 < 4; ++j2) {
      const int nloc = g * 16 + jj * 4 + j2;
      const uint4* vr = &v_lds[nloc * 8];
      int h = 0;
#pragma unroll
      for (int c = 0; c < 8; ++c) {
        const uint4 a = U[c];
        const uint4 b = vr[c];
        h += __builtin_popcount(a.x ^ b.x);   // -> v_bcnt_u32_b32 (acc form)
        h += __builtin_popcount(a.y ^ b.y);
        h += __builtin_popcount(a.z ^ b.z);
        h += __builtin_popcount(a.w ^ b.w);
      }
      res[j2] = __cosf(scale * (float)h);     // native v_cos_f32 path
    }
    float4 o;
    o.x = res[0]; o.y = res[1]; o.z = res[2]; o.w = res[3];
    *(float4*)(orow + jj * 4) = o;            // global_store_dwordx4
  }
}

// ---------------------------------------------------------------------------
extern "C" void kernel_launch(void* const* d_in, const int* in_sizes, int n_in,
                              void* d_out, int out_size, void* d_ws, size_t ws_size,
                              hipStream_t stream) {
  const float* emb1 = (const float*)d_in[0];   // [4096][128]
  const float* emb2 = (const float*)d_in[1];   // [8192][128]
  const float* r    = (const float*)d_in[2];   // [1024][128]
  const float* pi   = (const float*)d_in[3];   // [1]

  // workspace: packed codes, 12288 rows x 16 u64 = 1.5 MB
  unsigned long long* packed = (unsigned long long*)d_ws;

  dim3 g1(96, 8), b1(256);
  lsh_project_pack<<<g1, b1, 0, stream>>>(
      (const float4*)emb1, (const float4*)emb2, (const float4*)r, packed);

  dim3 g2(64, 128), b2(256);
  lsh_hamming_cos<<<g2, b2, 0, stream>>>(
      (const uint4*)packed,
      (const uint4*)(packed + (size_t)NROWS1 * 16),
      pi, (float*)d_out);
}

// Round 2
// 371.957 us; speedup vs baseline: 1.2970x; 1.2970x over previous
//
#include <hip/hip_runtime.h>
#include <hip/hip_bf16.h>
#include <stdint.h>

// LSH: project -> sign-bit-pack -> Hamming via xor+popcount -> cos
// packed codes in d_ws: [12288 rows][16 u64]; word w holds bits w*64..w*64+63,
// bit i of word = ballot bit i (lane i). Identical order for u and v.

#define NBITS   1024
#define NROWS1  4096
#define NROWS2  8192

// ---------------------------------------------------------------------------
// Kernel 1: projection + sign + bit-pack.
// Grid (96 rowBlks, 16 bitTiles), block 256 (4 waves).
// Block: 128 rows x 64 bits. Wave: 32 rows x 64 bits (bit = lane -> ballot
// yields the full u64 word). r tile 64x128 f32 = 32 KB LDS, chunk-swizzled.
// emb read as uniform-address global_load_dwordx4 (vmcnt — does NOT share a
// counter with ds_read, unlike the previous scalar-load version).
// ---------------------------------------------------------------------------
__global__ __launch_bounds__(256, 4) void lsh_project_pack(
    const float4* __restrict__ emb1,
    const float4* __restrict__ emb2,
    const float4* __restrict__ r4,
    unsigned long long* __restrict__ packed)
{
  __shared__ float4 r_lds[64 * 32];

  const int t = threadIdx.x;
  const int w = t >> 6;             // wave 0..3
  const int l = t & 63;             // lane = bit within tile
  const int rowBlk  = blockIdx.x;   // 0..95  (128 rows each)
  const int bitTile = blockIdx.y;   // 0..15  (64 bits each)

  // stage r tile: coalesced read, swizzled write (chunk c -> c ^ (row&7))
#pragma unroll
  for (int i = 0; i < 8; ++i) {
    const int idx = t + i * 256;
    const int row = idx >> 5;       // 0..63
    const int c   = idx & 31;
    r_lds[row * 32 + (c ^ (row & 7))] = r4[(bitTile * 64 + row) * 32 + c];
  }
  __syncthreads();

  const int key   = l & 7;
  const int rbase = l * 32;

  const int rowStart = rowBlk * 128;
  const bool side1   = rowStart < NROWS1;          // uniform (blockIdx-only)
  const float4* __restrict__ eb4 = side1 ? emb1 : emb2;
  const int rowBlkOff = side1 ? rowStart : (rowStart - NROWS1);

  for (int g = 0; g < 4; ++g) {
    const int rowLocal0 = w * 32 + g * 8;          // 8 rows this iteration
    const int ueb = (rowBlkOff + rowLocal0) * 32;  // float4 index (VGPR -> vector loads)

    float acc[8];
#pragma unroll
    for (int j = 0; j < 8; ++j) acc[j] = 0.0f;

#pragma unroll 2
    for (int c = 0; c < 32; ++c) {
      const float4 rv = r_lds[rbase + (c ^ key)];
#pragma unroll
      for (int j = 0; j < 8; ++j) {
        const float4 ev = eb4[ueb + j * 32 + c];   // uniform addr: 1 req, broadcast
        acc[j] = fmaf(ev.x, rv.x, acc[j]);
        acc[j] = fmaf(ev.y, rv.y, acc[j]);
        acc[j] = fmaf(ev.z, rv.z, acc[j]);
        acc[j] = fmaf(ev.w, rv.w, acc[j]);
      }
    }

#pragma unroll
    for (int j = 0; j < 8; ++j) {
      const unsigned long long m = __ballot(acc[j] > 0.0f);
      if (l == 0) {
        const int grow = rowStart + rowLocal0 + j;
        packed[(size_t)grow * 16 + bitTile] = m;
      }
    }
  }
}

// ---------------------------------------------------------------------------
// Kernel 2: Hamming (xor + fused popcount-accumulate) + cos.
// Grid (32 n-blocks, 128 m-blocks), block 256 (4 waves).
// Block tile: 32 rows x 256 cols. Wave w: rows w*8..+7. Lane l: cols l*4..+3.
// Thread: 8 rows x 4 cols register block, K split into 4 chunks of 8 words.
// U tile 4 KB (broadcast reads), V tile 32 KB (XOR-swizzled, key = l&7).
// Stores: wave writes 64 x float4 = 1 KB contiguous (fully coalesced).
// ---------------------------------------------------------------------------
__global__ __launch_bounds__(256, 4) void lsh_hamming_cos(
    const uint4* __restrict__ up,    // [4096][8]
    const uint4* __restrict__ vp,    // [8192][8]
    const float* __restrict__ pi_in,
    float* __restrict__ out)         // [4096][8192]
{
  __shared__ uint4 u_lds[32 * 8];    // 4 KB, linear
  __shared__ uint4 v_lds[256 * 8];   // 32 KB, swizzled

  const int t  = threadIdx.x;
  const int w  = t >> 6;
  const int l  = t & 63;
  const int n0 = blockIdx.x * 256;
  const int m0 = blockIdx.y * 32;

  // stage U tile (linear)
  u_lds[t] = up[(size_t)m0 * 8 + t];

  // stage V tile (swizzle uint4 slot: w4 ^ ((col>>2)&7))
#pragma unroll
  for (int i = 0; i < 8; ++i) {
    const int idx = t + i * 256;
    const int col = idx >> 3;
    const int w4  = idx & 7;
    v_lds[col * 8 + (w4 ^ ((col >> 2) & 7))] = vp[(size_t)n0 * 8 + idx];
  }
  __syncthreads();

  int h[8][4];
#pragma unroll
  for (int r = 0; r < 8; ++r)
#pragma unroll
    for (int j = 0; j < 4; ++j) h[r][j] = 0;

  const int vkey = l & 7;

#pragma unroll
  for (int kk = 0; kk < 4; ++kk) {   // 2 uint4 (8 words) per chunk
    // V fragment: 4 cols x 2 uint4 (lane-varying, swizzled -> conflict-free)
    uint4 V0[4], V1[4];
#pragma unroll
    for (int j = 0; j < 4; ++j) {
      const int col = l * 4 + j;
      V0[j] = v_lds[col * 8 + ((kk * 2 + 0) ^ vkey)];
      V1[j] = v_lds[col * 8 + ((kk * 2 + 1) ^ vkey)];
    }
#pragma unroll
    for (int r = 0; r < 8; ++r) {
      // U fragment: wave-uniform address -> LDS broadcast
      const int row = w * 8 + r;
      const uint4 U0 = u_lds[row * 8 + kk * 2 + 0];
      const uint4 U1 = u_lds[row * 8 + kk * 2 + 1];
#pragma unroll
      for (int j = 0; j < 4; ++j) {
        int s = h[r][j];
        s += __builtin_popcount(U0.x ^ V0[j].x);
        s += __builtin_popcount(U0.y ^ V0[j].y);
        s += __builtin_popcount(U0.z ^ V0[j].z);
        s += __builtin_popcount(U0.w ^ V0[j].w);
        s += __builtin_popcount(U1.x ^ V1[j].x);
        s += __builtin_popcount(U1.y ^ V1[j].y);
        s += __builtin_popcount(U1.z ^ V1[j].z);
        s += __builtin_popcount(U1.w ^ V1[j].w);
        h[r][j] = s;
      }
    }
  }

  const float scale = pi_in[0] * (1.0f / (float)NBITS);

#pragma unroll
  for (int r = 0; r < 8; ++r) {
    float4 o;
    o.x = __cosf(scale * (float)h[r][0]);
    o.y = __cosf(scale * (float)h[r][1]);
    o.z = __cosf(scale * (float)h[r][2]);
    o.w = __cosf(scale * (float)h[r][3]);
    const size_t row = (size_t)(m0 + w * 8 + r);
    *(float4*)(out + row * NROWS2 + n0 + l * 4) = o;  // 1 KB/wave contiguous
  }
}

// ---------------------------------------------------------------------------
extern "C" void kernel_launch(void* const* d_in, const int* in_sizes, int n_in,
                              void* d_out, int out_size, void* d_ws, size_t ws_size,
                              hipStream_t stream) {
  const float* emb1 = (const float*)d_in[0];   // [4096][128]
  const float* emb2 = (const float*)d_in[1];   // [8192][128]
  const float* r    = (const float*)d_in[2];   // [1024][128]
  const float* pi   = (const float*)d_in[3];   // [1]

  unsigned long long* packed = (unsigned long long*)d_ws;  // [12288][16]

  dim3 g1(96, 16), b1(256);
  lsh_project_pack<<<g1, b1, 0, stream>>>(
      (const float4*)emb1, (const float4*)emb2, (const float4*)r, packed);

  dim3 g2(32, 128), b2(256);
  lsh_hamming_cos<<<g2, b2, 0, stream>>>(
      (const uint4*)packed,
      (const uint4*)(packed + (size_t)NROWS1 * 16),
      pi, (float*)d_out);
}

// Round 3
// 239.433 us; speedup vs baseline: 2.0149x; 1.5535x over previous
//
#include <hip/hip_runtime.h>
#include <hip/hip_bf16.h>
#include <stdint.h>

// LSH: project -> sign-bit-pack -> Hamming via xor+popcount -> cos
// packed codes in d_ws: [12288 rows][16 u64]; word w holds bits w*64..+63,
// bit i of word = ballot bit i (lane i). Identical bit order for u and v,
// so xor-popcount Hamming is exact.

#define NBITS   1024
#define NROWS1  4096
#define NROWS2  8192

// ---------------------------------------------------------------------------
// Kernel 1: projection + sign + pack, GEMM-style (both operands via LDS).
// Grid (384 rowBlks, 4 bitTiles), block 256 (4 waves).
// Block tile: 32 rows x 256 bits, K=128 processed in 4 chunks of 32.
// Wave w owns rows w*8..+7 (all lanes share them -> broadcast LDS reads).
// Lane l owns bit-planes p*64+l (p=0..3) -> ballot gives u64 word p directly.
// e_lds [32][32] float4 = 16 KB (staged once, linear; reads are broadcast).
// r_lds [256][8] float4 = 32 KB per chunk (slot-swizzled s^(bit&7) ->
// conflict-free lane-varying ds_read_b128).
// Inner: per K-float4 step, 12 ds_reads feed 128 v_fma (VALU-dense).
// ---------------------------------------------------------------------------
__global__ __launch_bounds__(256, 3) void lsh_project_pack(
    const float4* __restrict__ emb1,
    const float4* __restrict__ emb2,
    const float4* __restrict__ r4,
    unsigned long long* __restrict__ packed)
{
  __shared__ float4 e_lds[32 * 32];    // [row][kchunk*8+ks], linear
  __shared__ float4 r_lds[256 * 8];    // [bit][slot^(bit&7)]

  const int t = threadIdx.x;
  const int w = t >> 6;
  const int l = t & 63;
  const int rowBlk  = blockIdx.x;      // 0..383 (32 rows each)
  const int bitTile = blockIdx.y;      // 0..3   (256 bits each)

  const int rowStart = rowBlk * 32;
  const bool side1   = rowStart < NROWS1;           // uniform (blockIdx-only)
  const float4* __restrict__ eb4 = side1 ? emb1 : emb2;
  const int rowOff = side1 ? rowStart : rowStart - NROWS1;

  // stage emb tile once (coalesced; 32 rows x 32 float4)
#pragma unroll
  for (int i = 0; i < 4; ++i) {
    const int idx = t + i * 256;
    e_lds[idx] = eb4[rowOff * 32 + idx];
  }

  float acc[8][4];
#pragma unroll
  for (int r = 0; r < 8; ++r)
#pragma unroll
    for (int p = 0; p < 4; ++p) acc[r][p] = 0.0f;

  const int key = l & 7;

  for (int ch = 0; ch < 4; ++ch) {
    __syncthreads();   // (ch=0: covers e_lds staging; ch>0: r_lds still in use)
    // stage r chunk: 256 bits x 8 float4, swizzled slot s -> s^(bit&7)
#pragma unroll
    for (int i = 0; i < 8; ++i) {
      const int idx = t + i * 256;
      const int bit = idx >> 3;        // 0..255
      const int s   = idx & 7;
      r_lds[bit * 8 + (s ^ (bit & 7))] =
          r4[(size_t)(bitTile * 256 + bit) * 32 + ch * 8 + s];
    }
    __syncthreads();

#pragma unroll
    for (int ks = 0; ks < 8; ++ks) {
      float4 rv[4];
#pragma unroll
      for (int p = 0; p < 4; ++p)
        rv[p] = r_lds[(p * 64 + l) * 8 + (ks ^ key)];   // conflict-free
      float4 ev[8];
#pragma unroll
      for (int r = 0; r < 8; ++r)
        ev[r] = e_lds[(w * 8 + r) * 32 + ch * 8 + ks];  // broadcast
#pragma unroll
      for (int r = 0; r < 8; ++r)
#pragma unroll
        for (int p = 0; p < 4; ++p) {
          acc[r][p] = fmaf(ev[r].x, rv[p].x, acc[r][p]);
          acc[r][p] = fmaf(ev[r].y, rv[p].y, acc[r][p]);
          acc[r][p] = fmaf(ev[r].z, rv[p].z, acc[r][p]);
          acc[r][p] = fmaf(ev[r].w, rv[p].w, acc[r][p]);
        }
    }
  }

  // pack: ballot over lanes (bit l of word p), lane r*4+p keeps word
  unsigned long long myword = 0;
#pragma unroll
  for (int r = 0; r < 8; ++r)
#pragma unroll
    for (int p = 0; p < 4; ++p) {
      const unsigned long long m = __ballot(acc[r][p] > 0.0f);
      if (l == r * 4 + p) myword = m;
    }
  if (l < 32) {
    const int row = rowStart + w * 8 + (l >> 2);
    packed[(size_t)row * 16 + bitTile * 4 + (l & 3)] = myword;
  }
}

// ---------------------------------------------------------------------------
// Kernel 2: Hamming (xor + fused popcount-accumulate) + cos.
// Grid (32 n-blocks, 64 m-blocks), block 256 (4 waves).
// Block tile: 64 rows x 256 cols. Thread: 8 rows x 8 cols (2 DS reads/output).
// Rows: w*16 + (l>>5)*8 ..+7; cols: (l&31)*4 + half*128 + j.
// U tile [64][8] uint4 = 8 KB linear (2-address broadcast reads = free).
// V tile [256][8] uint4 = 32 KB, slot-swizzled kk^((col>>2)&7) -> conflict-free.
// Inner: per V-read, 8 rows x (4 xor + 4 v_bcnt-acc) = 64 VALU.
// Stores: two 512 B contiguous segments per wave-store instruction.
// ---------------------------------------------------------------------------
__global__ __launch_bounds__(256, 3) void lsh_hamming_cos(
    const uint4* __restrict__ up,    // [4096][8]
    const uint4* __restrict__ vp,    // [8192][8]
    const float* __restrict__ pi_in,
    float* __restrict__ out)         // [4096][8192]
{
  __shared__ uint4 u_lds[64 * 8];    // 8 KB, linear
  __shared__ uint4 v_lds[256 * 8];   // 32 KB, swizzled

  const int t  = threadIdx.x;
  const int w  = t >> 6;
  const int l  = t & 63;
  const int n0 = blockIdx.x * 256;
  const int m0 = blockIdx.y * 64;

  // stage U tile (linear, coalesced)
#pragma unroll
  for (int i = 0; i < 2; ++i)
    u_lds[t + i * 256] = up[(size_t)m0 * 8 + t + i * 256];

  // stage V tile (swizzle uint4 slot: w4 -> w4 ^ ((col>>2)&7))
#pragma unroll
  for (int i = 0; i < 8; ++i) {
    const int idx = t + i * 256;
    const int col = idx >> 3;
    const int w4  = idx & 7;
    v_lds[col * 8 + (w4 ^ ((col >> 2) & 7))] = vp[(size_t)n0 * 8 + idx];
  }
  __syncthreads();

  int h[8][8];
#pragma unroll
  for (int r = 0; r < 8; ++r)
#pragma unroll
    for (int j = 0; j < 8; ++j) h[r][j] = 0;

  const int key  = l & 7;
  const int row0 = w * 16 + (l >> 5) * 8;   // thread's first row (block-local)
  const int c0   = (l & 31) * 4;            // thread's first col (block-local)

#pragma unroll
  for (int kk = 0; kk < 8; ++kk) {          // one uint4 (128 bits) per step
    uint4 U[8];
#pragma unroll
    for (int r = 0; r < 8; ++r)
      U[r] = u_lds[(row0 + r) * 8 + kk];    // 2-address broadcast: free
    const int slot = kk ^ key;
#pragma unroll
    for (int half = 0; half < 2; ++half) {
#pragma unroll
      for (int j = 0; j < 4; ++j) {
        const uint4 V = v_lds[(c0 + half * 128 + j) * 8 + slot];
#pragma unroll
        for (int r = 0; r < 8; ++r) {
          int s = h[r][half * 4 + j];
          s += __builtin_popcount(U[r].x ^ V.x);   // v_bcnt_u32_b32 acc-fused
          s += __builtin_popcount(U[r].y ^ V.y);
          s += __builtin_popcount(U[r].z ^ V.z);
          s += __builtin_popcount(U[r].w ^ V.w);
          h[r][half * 4 + j] = s;
        }
      }
    }
  }

  const float scale = pi_in[0] * (1.0f / (float)NBITS);

#pragma unroll
  for (int r = 0; r < 8; ++r) {
    const size_t row = (size_t)(m0 + row0 + r);
#pragma unroll
    for (int half = 0; half < 2; ++half) {
      float4 o;
      o.x = __cosf(scale * (float)h[r][half * 4 + 0]);
      o.y = __cosf(scale * (float)h[r][half * 4 + 1]);
      o.z = __cosf(scale * (float)h[r][half * 4 + 2]);
      o.w = __cosf(scale * (float)h[r][half * 4 + 3]);
      *(float4*)(out + row * NROWS2 + n0 + c0 + half * 128) = o;
    }
  }
}

// ---------------------------------------------------------------------------
extern "C" void kernel_launch(void* const* d_in, const int* in_sizes, int n_in,
                              void* d_out, int out_size, void* d_ws, size_t ws_size,
                              hipStream_t stream) {
  const float* emb1 = (const float*)d_in[0];   // [4096][128]
  const float* emb2 = (const float*)d_in[1];   // [8192][128]
  const float* r    = (const float*)d_in[2];   // [1024][128]
  const float* pi   = (const float*)d_in[3];   // [1]

  unsigned long long* packed = (unsigned long long*)d_ws;  // [12288][16]

  dim3 g1(384, 4), b1(256);
  lsh_project_pack<<<g1, b1, 0, stream>>>(
      (const float4*)emb1, (const float4*)emb2, (const float4*)r, packed);

  dim3 g2(32, 64), b2(256);
  lsh_hamming_cos<<<g2, b2, 0, stream>>>(
      (const uint4*)packed,
      (const uint4*)(packed + (size_t)NROWS1 * 16),
      pi, (float*)d_out);
}